// Round 21
// baseline (180.954 us; speedup 1.0000x reference)
//
#include <hip/hip_runtime.h>
#include <hip/hip_bf16.h>
#include <stdint.h>

// B=2, SQ=2048, SE=2048, SKV=4096, H=1024, NH=16, HD=64
// fp32 in/out; internal compute bf16 MFMA.

typedef __attribute__((ext_vector_type(8))) short short8;
typedef __attribute__((ext_vector_type(4))) float f32x4;
typedef __attribute__((ext_vector_type(16))) float f32x16;
typedef __attribute__((ext_vector_type(4))) unsigned short us4;
typedef __attribute__((ext_vector_type(4))) unsigned int u32x4;

// may_alias types for LDS handoffs (R3 lesson: TBAA reorder).
typedef __attribute__((ext_vector_type(8), may_alias)) short short8a;
typedef __attribute__((ext_vector_type(4), may_alias)) float f32x4a;
typedef __attribute__((may_alias)) float floata;

#define DEV static __device__ __forceinline__

DEV unsigned short f2bf(float f) {
  unsigned int u = __builtin_bit_cast(unsigned int, f);
  u += 0x7fffu + ((u >> 16) & 1u);   // RNE
  return (unsigned short)(u >> 16);
}

DEV float exp2_(float x) {
#if __has_builtin(__builtin_amdgcn_exp2f)
  return __builtin_amdgcn_exp2f(x);
#else
  float r; asm("v_exp_f32 %0, %1" : "=v"(r) : "v"(x)); return r;
#endif
}

DEV unsigned int cvtpk_bf16(float lo, float hi) {
  unsigned int r;
  asm("v_cvt_pk_bf16_f32 %0, %1, %2" : "=v"(r) : "v"(lo), "v"(hi));
  return r;
}

DEV void g2lds16(const void* g, void* l) {
  __builtin_amdgcn_global_load_lds((const __attribute__((address_space(1))) void*)g,
                                   (__attribute__((address_space(3))) void*)l, 16, 0, 0);
}

// ---------- input conversion: all_hs -> bf16; blocks >= 8192 premultiply the mask ----------
__global__ __launch_bounds__(256) void convert_allhs(const float* __restrict__ hid,
                                                     const float* __restrict__ enc,
                                                     unsigned short* __restrict__ ah,
                                                     const float* __restrict__ mask,
                                                     float* __restrict__ mask2) {
  if (blockIdx.x >= 8192) {
    int i = (blockIdx.x - 8192) * 256 + threadIdx.x;
    f32x4 v = *(const f32x4*)(mask + i * 4);
    *(f32x4*)(mask2 + i * 4) = v * 1.4426950408889634f;
    return;
  }
  int idx = blockIdx.x * 256 + threadIdx.x;
  const int perB = 4096 * 256;
  int b = idx / perB, r = idx - b * perB;
  int s = r >> 8, c4 = r & 255;
  const float* srcrow = (s < 2048) ? hid + (size_t)(b * 2048 + s) * 1024
                                   : enc + (size_t)(b * 2048 + (s - 2048)) * 1024;
  f32x4 v = *(const f32x4*)(srcrow + c4 * 4);
  us4 o;
  o[0] = f2bf(v[0]); o[1] = f2bf(v[1]); o[2] = f2bf(v[2]); o[3] = f2bf(v[3]);
  *(us4*)(ah + (size_t)idx * 4) = o;
}

// ---------- merged weight transpose: Wt[n][k] = bf16(W[k][n]) for Wq,Wk,Wv ----------
__global__ __launch_bounds__(256) void transpose_w3(const float* __restrict__ Wq,
                                                    const float* __restrict__ Wk,
                                                    const float* __restrict__ Wv,
                                                    unsigned short* __restrict__ WtBase) {
  __shared__ unsigned short t[64][65];
  const int z = blockIdx.z;
  const float* W = (z == 0) ? Wq : (z == 1) ? Wk : Wv;
  unsigned short* Wt = WtBase + (size_t)z * 1048576;
  int k0 = blockIdx.y * 64, n0 = blockIdx.x * 64;
  int tid = threadIdx.x;
#pragma unroll
  for (int rep = 0; rep < 16; rep++) {
    int idx = rep * 256 + tid;
    int kk = idx >> 6, nn = idx & 63;
    t[kk][nn] = f2bf(W[(size_t)(k0 + kk) * 1024 + n0 + nn]);
  }
  __syncthreads();
#pragma unroll
  for (int rep = 0; rep < 16; rep++) {
    int idx = rep * 256 + tid;
    int nn = idx >> 6, kk = idx & 63;
    Wt[(size_t)(n0 + nn) * 1024 + k0 + kk] = t[kk][nn];
  }
}

// ---------- merged NT GEMM, BK=64 (R17-proven): Q + K + V in ONE 1280-block dispatch ----
__global__ __launch_bounds__(256) void gemm_all(const unsigned short* __restrict__ WTQ,
                                                const unsigned short* __restrict__ WTK,
                                                const unsigned short* __restrict__ WTV,
                                                const unsigned short* __restrict__ AH,
                                                const float* __restrict__ bq,
                                                const float* __restrict__ bk,
                                                const float* __restrict__ bv,
                                                unsigned short* __restrict__ Qout,
                                                unsigned short* __restrict__ Kout,
                                                unsigned short* __restrict__ Vout,
                                                float qscale) {
  __shared__ unsigned short ldsA[2][128 * 32];   // [k-sub][row][32k]
  __shared__ unsigned short ldsB[2][128 * 32];

  int id = blockIdx.x;
  int f2 = (id & 7) * 160 + (id >> 3);

  const unsigned short *A, *Bm;
  const float* bias;
  unsigned short* outb;
  int S, mode, r0, c0;
  float osc = 1.0f;
  if (f2 < 256) {                       // Q
    int t = f2;
    int b = t >> 7; t &= 127;
    c0 = (t & 15) * 128; r0 = (t >> 4) * 128;
    A = WTQ; Bm = AH + (size_t)b * 4194304; bias = bq;
    outb = Qout + (size_t)b * 2097152; S = 2048; mode = 0; osc = qscale;
  } else if (f2 < 768) {                // K
    int t = f2 - 256;
    int b = t >> 8; t &= 255;
    c0 = (t & 31) * 128; r0 = (t >> 5) * 128;
    A = WTK; Bm = AH + (size_t)b * 4194304; bias = bk;
    outb = Kout + (size_t)b * 4194304; S = 4096; mode = 0;
  } else {                              // V (transposed out)
    int t = f2 - 768;
    int b = t >> 8; t &= 255;
    c0 = (t & 7) * 128; r0 = (t >> 3) * 128;
    A = AH + (size_t)b * 4194304; Bm = WTV; bias = bv;
    outb = Vout + (size_t)b * 4194304; S = 4096; mode = 1;
  }

  const int tid = threadIdx.x, w = tid >> 6, l = tid & 63;
  const int wr = w >> 1, wc = w & 1;
  const int lrow = l >> 2;                       // 4 lanes per row
  const int lc = l & 15, g = l >> 4;

  f32x4 acc[4][4];
#pragma unroll
  for (int i = 0; i < 4; i++)
#pragma unroll
    for (int j = 0; j < 4; j++) acc[i][j] = (f32x4){0.f, 0.f, 0.f, 0.f};

  for (int k0 = 0; k0 < 1024; k0 += 64) {
#pragma unroll
    for (int c = 0; c < 4; c++) {
      const int cc = w * 4 + c;
      const int sub = cc & 1, rr = (cc >> 1) * 16 + lrow;
      const int kc = sub * 4 + (l & 3);
      g2lds16(A + (size_t)(r0 + rr) * 1024 + k0 + kc * 8,
              (char*)ldsA + sub * 8192 + (cc >> 1) * 1024);
      g2lds16(Bm + (size_t)(c0 + rr) * 1024 + k0 + kc * 8,
              (char*)ldsB + sub * 8192 + (cc >> 1) * 1024);
    }
    __syncthreads();
#pragma unroll
    for (int kk = 0; kk < 2; kk++) {
      short8 af[4], bf[4];
#pragma unroll
      for (int f = 0; f < 4; f++) {
        af[f] = *(const short8*)((const char*)ldsA + kk * 8192 + (wr * 64 + f * 16 + lc) * 64 + g * 16);
        bf[f] = *(const short8*)((const char*)ldsB + kk * 8192 + (wc * 64 + f * 16 + lc) * 64 + g * 16);
      }
#pragma unroll
      for (int fr = 0; fr < 4; fr++)
#pragma unroll
        for (int fc = 0; fc < 4; fc++)
          acc[fr][fc] = __builtin_amdgcn_mfma_f32_16x16x32_bf16(af[fr], bf[fc], acc[fr][fc], 0, 0, 0);
    }
    __syncthreads();
  }

#pragma unroll
  for (int fr = 0; fr < 4; fr++) {
    int rb = r0 + wr * 64 + fr * 16 + g * 4;
    float bv4[4];
    if (mode == 0) {
#pragma unroll
      for (int i = 0; i < 4; i++) bv4[i] = bias[rb + i];
    }
#pragma unroll
    for (int fc = 0; fc < 4; fc++) {
      int c = c0 + wc * 64 + fc * 16 + lc;
      float bc = (mode == 0) ? 0.f : bias[c];
      us4 pk;
#pragma unroll
      for (int i = 0; i < 4; i++) {
        float v = (acc[fr][fc][i] + (mode == 0 ? bv4[i] : bc)) * osc;
        pk[i] = f2bf(v);
      }
      size_t addr;
      if (mode == 0) addr = ((size_t)(rb >> 6) * S + c) * 64 + (rb & 63);
      else           addr = (size_t)c * S + rb;
      *(us4*)(outb + addr) = pk;
    }
  }
}

// ---------- flash attention v21: ls via ones-MFMA (VALU relief) ----------
// R20 ledger: VALU is the busiest pipe (49%) and per tile 32 serial v_add_f32
// accumulate lsr. Replace with lsacc = mfma(onesA, bfr, lsacc): A==1 makes every
// accumulator row D[r][q] = sum_k P[k][q], so ls_tot = lsacc[0] -- no adds, no
// final shfl, and ls sums the SAME bf16-rounded P that PV consumes (R6-R11-proven
// pattern). Cost: +16 AGPR (same occupancy band). Mask stays rank-1 MFMA (R20).
__global__ __launch_bounds__(256) void attn_kernel(const unsigned short* __restrict__ Q,
                                                   const unsigned short* __restrict__ K,
                                                   const unsigned short* __restrict__ Vt,
                                                   const float* __restrict__ mask2,
                                                   float* __restrict__ out) {
  __shared__ __align__(16) char lds[32768];
  // buf*16384          : K tile [64 kv][128B], slot j holds chunk j^(kv&7)
  // buf*16384 + 8192   : V tile [64 d][128B],  slot j holds chunk j^(d&7)

  // XCD-chunked swizzle (T1), bijective over 512 blocks (512 % 8 == 0)
  int flat = blockIdx.x + 16 * (blockIdx.y + 16 * blockIdx.z);   // 0..511
  int f2 = (flat & 7) * 64 + (flat >> 3);
  const int qt = f2 & 15, h = (f2 >> 4) & 15, b = f2 >> 8;

  const int tid = threadIdx.x, w = tid >> 6, l = tid & 63;
  const int lq = l & 31, h2 = l >> 5;
  const int isV = w >> 1, half = w & 1;          // staging role
  const int srow8 = l >> 3, slot = l & 7;

  const unsigned short* Qb = Q + ((size_t)(b * 16 + h) * 2048) * 64;
  const unsigned short* Kb = K + ((size_t)(b * 16 + h) * 4096) * 64;
  const unsigned short* Vb = Vt + ((size_t)(b * 16 + h) * 64) * 4096;
  const float* mk = mask2 + (size_t)b * 4096;
  const int sq0 = qt * 128 + w * 32;

  // Q fragments (B-operand of 32x32x16): lane holds q=lq, d = ks*16 + h2*8 + j
  short8 qf[4];
#pragma unroll
  for (int ks = 0; ks < 4; ks++)
    qf[ks] = *(const short8*)(Qb + (size_t)(sq0 + lq) * 64 + ks * 16 + h2 * 8);

  // constant B-frag with B[k=0][q]=1 (h2==0, j==0 element = bf16 1.0) for the mask
  const u32x4 obp = (u32x4){(h2 == 0) ? 0x00003f80u : 0u, 0u, 0u, 0u};
  const short8 onesB = __builtin_bit_cast(short8, obp);
  // all-ones A-frag for the ls-sum MFMA
  short8 onesA;
#pragma unroll
  for (int i = 0; i < 8; i++) onesA[i] = (short)0x3f80;

  f32x16 ctx[2];
#pragma unroll
  for (int d = 0; d < 2; d++)
#pragma unroll
    for (int r = 0; r < 16; r++) ctx[d][r] = 0.f;
  f32x16 lsacc;
#pragma unroll
  for (int r = 0; r < 16; r++) lsacc[r] = 0.f;

  // ---- stage tile 0 into buf 0 ----
  {
    char* base = lds + isV * 8192;
    if (!isV) {
#pragma unroll
      for (int c = 0; c < 4; c++) {
        int kr = half * 32 + c * 8 + srow8;
        g2lds16(Kb + (size_t)kr * 64 + (slot ^ (kr & 7)) * 8, base + (half * 32 + c * 8) * 128);
      }
    } else {
#pragma unroll
      for (int c = 0; c < 4; c++) {
        int dr = half * 32 + c * 8 + srow8;
        g2lds16(Vb + (size_t)dr * 4096 + (slot ^ (dr & 7)) * 8, base + (half * 32 + c * 8) * 128);
      }
    }
  }
  __syncthreads();

  int buf = 0;
  for (int t = 0; t < 64; t++) {
    const int s0 = t * 64;

    // mask scalars FIRST (oldest vmcnt slots; their wait leaves the DMA in flight)
    float mval0 = mk[s0 + lq];
    float mval1 = mk[s0 + 32 + lq];

    // ---- issue DMA for tile t+1 into buf^1 (lands during compute below) ----
    if (t < 63) {
      char* base = lds + (buf ^ 1) * 16384 + isV * 8192;
      if (!isV) {
#pragma unroll
        for (int c = 0; c < 4; c++) {
          int kr = half * 32 + c * 8 + srow8;
          g2lds16(Kb + (size_t)(s0 + 64 + kr) * 64 + (slot ^ (kr & 7)) * 8,
                  base + (half * 32 + c * 8) * 128);
        }
      } else {
#pragma unroll
        for (int c = 0; c < 4; c++) {
          int dr = half * 32 + c * 8 + srow8;
          g2lds16(Vb + (size_t)dr * 4096 + (s0 + 64) + (slot ^ (dr & 7)) * 8,
                  base + (half * 32 + c * 8) * 128);
        }
      }
    }

    const char* kbase = lds + buf * 16384;
    const char* vbase = lds + buf * 16384 + 8192;

    // ---- QK^T per 32-kv sub; C-init = rank-1 mask MFMA; P in registers ----
    short8 bfr[2][2];   // [sub][k2] PV B-fragments
#pragma unroll
    for (int sub = 0; sub < 2; sub++) {
      // mask A-frag: A[kv=lq][k=0] = bf16(m2), h2==0 lanes only
      unsigned int mw0 = (h2 == 0) ? cvtpk_bf16(sub ? mval1 : mval0, 0.f) : 0u;
      u32x4 mAp = (u32x4){mw0, 0u, 0u, 0u};
      short8 mA = __builtin_bit_cast(short8, mAp);
      f32x16 z;
#pragma unroll
      for (int r = 0; r < 16; r++) z[r] = 0.f;
      z = __builtin_amdgcn_mfma_f32_32x32x16_bf16(mA, onesB, z, 0, 0, 0);
#pragma unroll
      for (int ks = 0; ks < 4; ks++) {
        short8 kf = *(const short8*)(kbase + (sub * 32 + lq) * 128 + (((ks * 2 + h2) ^ (lq & 7)) << 4));
        z = __builtin_amdgcn_mfma_f32_32x32x16_bf16(kf, qf[ks], z, 0, 0, 0);
      }
      float p[16];
#pragma unroll
      for (int r = 0; r < 16; r++) p[r] = exp2_(z[r]);
      unsigned int X[4], Y[4];
#pragma unroll
      for (int br = 0; br < 4; br++) {
        X[br] = cvtpk_bf16(p[br * 4 + 0], p[br * 4 + 1]);
        Y[br] = cvtpk_bf16(p[br * 4 + 2], p[br * 4 + 3]);
      }
#pragma unroll
      for (int k2 = 0; k2 < 2; k2++) {
        // swap(D=X[2k2], S=X[2k2+1]): D' = w0 (j0,j1), S' = w2 (j4,j5); Y -> w1, w3.
        unsigned int xd = X[2 * k2], xs = X[2 * k2 + 1];
        asm("v_permlane32_swap_b32 %0, %1" : "+v"(xd), "+v"(xs));
        unsigned int yd = Y[2 * k2], ys = Y[2 * k2 + 1];
        asm("v_permlane32_swap_b32 %0, %1" : "+v"(yd), "+v"(ys));
        u32x4 packed = (u32x4){xd, yd, xs, ys};
        bfr[sub][k2] = __builtin_bit_cast(short8, packed);
      }
    }

    // ---- PV: ctx[dsub] += mfma(V-frag, P-frag) ; ls += mfma(ones, P-frag) ----
#pragma unroll
    for (int dsub = 0; dsub < 2; dsub++)
#pragma unroll
      for (int sub = 0; sub < 2; sub++)
#pragma unroll
        for (int k2 = 0; k2 < 2; k2++) {
          short8 vf = *(const short8*)(vbase + (dsub * 32 + lq) * 128 +
                                       (((sub * 4 + k2 * 2 + h2) ^ (lq & 7)) << 4));
          ctx[dsub] = __builtin_amdgcn_mfma_f32_32x32x16_bf16(vf, bfr[sub][k2], ctx[dsub], 0, 0, 0);
        }
#pragma unroll
    for (int sub = 0; sub < 2; sub++)
#pragma unroll
      for (int k2 = 0; k2 < 2; k2++)
        lsacc = __builtin_amdgcn_mfma_f32_32x32x16_bf16(onesA, bfr[sub][k2], lsacc, 0, 0, 0);

    __syncthreads();   // drains DMA of t+1; all waves done reading buf
    buf ^= 1;
  }

  // every lsacc row holds the full kv-sum for this lane's q
  float inv = 1.f / lsacc[0];

  // ---- epilogue: direct write (no merge) ----
  size_t orow = (size_t)(b * 2048 + sq0 + lq);
#pragma unroll
  for (int dsub = 0; dsub < 2; dsub++)
#pragma unroll
    for (int br = 0; br < 4; br++) {
      int d0 = dsub * 32 + br * 8 + h2 * 4;
      f32x4 o = (f32x4){ctx[dsub][br * 4 + 0], ctx[dsub][br * 4 + 1],
                        ctx[dsub][br * 4 + 2], ctx[dsub][br * 4 + 3]} * inv;
      *(f32x4*)(out + orow * 1024 + h * 64 + d0) = o;
    }
}

// ---------- launcher ----------
extern "C" void kernel_launch(void* const* d_in, const int* in_sizes, int n_in,
                              void* d_out, int out_size, void* d_ws, size_t ws_size,
                              hipStream_t stream) {
  const float* hid = (const float*)d_in[0];
  const float* enc = (const float*)d_in[1];
  const float* mask = (const float*)d_in[2];
  const float* Wq = (const float*)d_in[3];
  const float* bq = (const float*)d_in[4];
  const float* Wk = (const float*)d_in[5];
  const float* bk = (const float*)d_in[6];
  const float* Wv = (const float*)d_in[7];
  const float* bv = (const float*)d_in[8];

  unsigned short* ws = (unsigned short*)d_ws;
  unsigned short* WTQ = ws;                    // 1M elems (WTQ/WTK/WTV contiguous)
  unsigned short* WTK = ws + 1048576;          // 1M
  unsigned short* WTV = ws + 2097152;          // 1M
  unsigned short* AH  = ws + 3145728;          // 8M  [B][4096][1024]
  unsigned short* Qb  = ws + 11534336;         // 4M  [B][16][2048][64]
  unsigned short* Kb  = ws + 15728640;         // 8M  [B][16][4096][64]
  unsigned short* VT  = ws + 24117248;         // 8M  [B][16][64][4096]
  float* mask2 = (float*)(ws + 32505856);      // 8192 fp32

  const float QSCALE = 0.18033688011112042f;   // 0.125 * log2(e), folded into Q projection

  convert_allhs<<<8200, 256, 0, stream>>>(hid, enc, AH, mask, mask2);
  transpose_w3<<<dim3(16, 16, 3), 256, 0, stream>>>(Wq, Wk, Wv, WTQ);

  gemm_all<<<1280, 256, 0, stream>>>(WTQ, WTK, WTV, AH, bq, bk, bv, Qb, Kb, VT, QSCALE);

  attn_kernel<<<dim3(16, 16, 2), 256, 0, stream>>>(Qb, Kb, VT, mask2, (float*)d_out);
}

// Round 22
// 174.596 us; speedup vs baseline: 1.0364x; 1.0364x over previous
//
#include <hip/hip_runtime.h>
#include <hip/hip_bf16.h>
#include <stdint.h>

// B=2, SQ=2048, SE=2048, SKV=4096, H=1024, NH=16, HD=64
// fp32 in/out; internal compute bf16 MFMA.

typedef __attribute__((ext_vector_type(8))) short short8;
typedef __attribute__((ext_vector_type(4))) float f32x4;
typedef __attribute__((ext_vector_type(16))) float f32x16;
typedef __attribute__((ext_vector_type(4))) unsigned short us4;
typedef __attribute__((ext_vector_type(4))) unsigned int u32x4;

// may_alias types for LDS handoffs (R3 lesson: TBAA reorder).
typedef __attribute__((ext_vector_type(8), may_alias)) short short8a;
typedef __attribute__((ext_vector_type(4), may_alias)) float f32x4a;
typedef __attribute__((may_alias)) float floata;

#define DEV static __device__ __forceinline__

DEV unsigned short f2bf(float f) {
  unsigned int u = __builtin_bit_cast(unsigned int, f);
  u += 0x7fffu + ((u >> 16) & 1u);   // RNE
  return (unsigned short)(u >> 16);
}

DEV float exp2_(float x) {
#if __has_builtin(__builtin_amdgcn_exp2f)
  return __builtin_amdgcn_exp2f(x);
#else
  float r; asm("v_exp_f32 %0, %1" : "=v"(r) : "v"(x)); return r;
#endif
}

DEV unsigned int cvtpk_bf16(float lo, float hi) {
  unsigned int r;
  asm("v_cvt_pk_bf16_f32 %0, %1, %2" : "=v"(r) : "v"(lo), "v"(hi));
  return r;
}

DEV void g2lds16(const void* g, void* l) {
  __builtin_amdgcn_global_load_lds((const __attribute__((address_space(1))) void*)g,
                                   (__attribute__((address_space(3))) void*)l, 16, 0, 0);
}

// ---------- input conversion: all_hs -> bf16; blocks >= 8192 premultiply the mask ----------
__global__ __launch_bounds__(256) void convert_allhs(const float* __restrict__ hid,
                                                     const float* __restrict__ enc,
                                                     unsigned short* __restrict__ ah,
                                                     const float* __restrict__ mask,
                                                     float* __restrict__ mask2) {
  if (blockIdx.x >= 8192) {
    int i = (blockIdx.x - 8192) * 256 + threadIdx.x;
    f32x4 v = *(const f32x4*)(mask + i * 4);
    *(f32x4*)(mask2 + i * 4) = v * 1.4426950408889634f;
    return;
  }
  int idx = blockIdx.x * 256 + threadIdx.x;
  const int perB = 4096 * 256;
  int b = idx / perB, r = idx - b * perB;
  int s = r >> 8, c4 = r & 255;
  const float* srcrow = (s < 2048) ? hid + (size_t)(b * 2048 + s) * 1024
                                   : enc + (size_t)(b * 2048 + (s - 2048)) * 1024;
  f32x4 v = *(const f32x4*)(srcrow + c4 * 4);
  us4 o;
  o[0] = f2bf(v[0]); o[1] = f2bf(v[1]); o[2] = f2bf(v[2]); o[3] = f2bf(v[3]);
  *(us4*)(ah + (size_t)idx * 4) = o;
}

// ---------- merged weight transpose: Wt[n][k] = bf16(W[k][n]) for Wq,Wk,Wv ----------
__global__ __launch_bounds__(256) void transpose_w3(const float* __restrict__ Wq,
                                                    const float* __restrict__ Wk,
                                                    const float* __restrict__ Wv,
                                                    unsigned short* __restrict__ WtBase) {
  __shared__ unsigned short t[64][65];
  const int z = blockIdx.z;
  const float* W = (z == 0) ? Wq : (z == 1) ? Wk : Wv;
  unsigned short* Wt = WtBase + (size_t)z * 1048576;
  int k0 = blockIdx.y * 64, n0 = blockIdx.x * 64;
  int tid = threadIdx.x;
#pragma unroll
  for (int rep = 0; rep < 16; rep++) {
    int idx = rep * 256 + tid;
    int kk = idx >> 6, nn = idx & 63;
    t[kk][nn] = f2bf(W[(size_t)(k0 + kk) * 1024 + n0 + nn]);
  }
  __syncthreads();
#pragma unroll
  for (int rep = 0; rep < 16; rep++) {
    int idx = rep * 256 + tid;
    int nn = idx >> 6, kk = idx & 63;
    Wt[(size_t)(n0 + nn) * 1024 + k0 + kk] = t[kk][nn];
  }
}

// ---------- merged NT GEMM, BK=64 (R17-proven): Q + K + V in ONE 1280-block dispatch ----
__global__ __launch_bounds__(256) void gemm_all(const unsigned short* __restrict__ WTQ,
                                                const unsigned short* __restrict__ WTK,
                                                const unsigned short* __restrict__ WTV,
                                                const unsigned short* __restrict__ AH,
                                                const float* __restrict__ bq,
                                                const float* __restrict__ bk,
                                                const float* __restrict__ bv,
                                                unsigned short* __restrict__ Qout,
                                                unsigned short* __restrict__ Kout,
                                                unsigned short* __restrict__ Vout,
                                                float qscale) {
  __shared__ unsigned short ldsA[2][128 * 32];   // [k-sub][row][32k]
  __shared__ unsigned short ldsB[2][128 * 32];

  int id = blockIdx.x;
  int f2 = (id & 7) * 160 + (id >> 3);

  const unsigned short *A, *Bm;
  const float* bias;
  unsigned short* outb;
  int S, mode, r0, c0;
  float osc = 1.0f;
  if (f2 < 256) {                       // Q
    int t = f2;
    int b = t >> 7; t &= 127;
    c0 = (t & 15) * 128; r0 = (t >> 4) * 128;
    A = WTQ; Bm = AH + (size_t)b * 4194304; bias = bq;
    outb = Qout + (size_t)b * 2097152; S = 2048; mode = 0; osc = qscale;
  } else if (f2 < 768) {                // K
    int t = f2 - 256;
    int b = t >> 8; t &= 255;
    c0 = (t & 31) * 128; r0 = (t >> 5) * 128;
    A = WTK; Bm = AH + (size_t)b * 4194304; bias = bk;
    outb = Kout + (size_t)b * 4194304; S = 4096; mode = 0;
  } else {                              // V (transposed out)
    int t = f2 - 768;
    int b = t >> 8; t &= 255;
    c0 = (t & 7) * 128; r0 = (t >> 3) * 128;
    A = AH + (size_t)b * 4194304; Bm = WTV; bias = bv;
    outb = Vout + (size_t)b * 4194304; S = 4096; mode = 1;
  }

  const int tid = threadIdx.x, w = tid >> 6, l = tid & 63;
  const int wr = w >> 1, wc = w & 1;
  const int lrow = l >> 2;                       // 4 lanes per row
  const int lc = l & 15, g = l >> 4;

  f32x4 acc[4][4];
#pragma unroll
  for (int i = 0; i < 4; i++)
#pragma unroll
    for (int j = 0; j < 4; j++) acc[i][j] = (f32x4){0.f, 0.f, 0.f, 0.f};

  for (int k0 = 0; k0 < 1024; k0 += 64) {
#pragma unroll
    for (int c = 0; c < 4; c++) {
      const int cc = w * 4 + c;
      const int sub = cc & 1, rr = (cc >> 1) * 16 + lrow;
      const int kc = sub * 4 + (l & 3);
      g2lds16(A + (size_t)(r0 + rr) * 1024 + k0 + kc * 8,
              (char*)ldsA + sub * 8192 + (cc >> 1) * 1024);
      g2lds16(Bm + (size_t)(c0 + rr) * 1024 + k0 + kc * 8,
              (char*)ldsB + sub * 8192 + (cc >> 1) * 1024);
    }
    __syncthreads();
#pragma unroll
    for (int kk = 0; kk < 2; kk++) {
      short8 af[4], bf[4];
#pragma unroll
      for (int f = 0; f < 4; f++) {
        af[f] = *(const short8*)((const char*)ldsA + kk * 8192 + (wr * 64 + f * 16 + lc) * 64 + g * 16);
        bf[f] = *(const short8*)((const char*)ldsB + kk * 8192 + (wc * 64 + f * 16 + lc) * 64 + g * 16);
      }
#pragma unroll
      for (int fr = 0; fr < 4; fr++)
#pragma unroll
        for (int fc = 0; fc < 4; fc++)
          acc[fr][fc] = __builtin_amdgcn_mfma_f32_16x16x32_bf16(af[fr], bf[fc], acc[fr][fc], 0, 0, 0);
    }
    __syncthreads();
  }

#pragma unroll
  for (int fr = 0; fr < 4; fr++) {
    int rb = r0 + wr * 64 + fr * 16 + g * 4;
    float bv4[4];
    if (mode == 0) {
#pragma unroll
      for (int i = 0; i < 4; i++) bv4[i] = bias[rb + i];
    }
#pragma unroll
    for (int fc = 0; fc < 4; fc++) {
      int c = c0 + wc * 64 + fc * 16 + lc;
      float bc = (mode == 0) ? 0.f : bias[c];
      us4 pk;
#pragma unroll
      for (int i = 0; i < 4; i++) {
        float v = (acc[fr][fc][i] + (mode == 0 ? bv4[i] : bc)) * osc;
        pk[i] = f2bf(v);
      }
      size_t addr;
      if (mode == 0) addr = ((size_t)(rb >> 6) * S + c) * 64 + (rb & 63);
      else           addr = (size_t)c * S + rb;
      *(us4*)(outb + addr) = pk;
    }
  }
}

// ---------- flash attention v22: 128-kv tiles (2x the R21 tile), half the barriers ----------
// R21 lesson: pipe-shifting is null -- the kernel is fixed-cost-per-tile bound
// (2 barriers + vmcnt(0) DMA drain x 64 iters) with occupancy pinned by the register
// band (2 blocks/CU) while LDS used only 32KB/160KB. v22: tile = 128 kv laid out as
// TWO verbatim copies of the proven 64-kv tile ([K0|K1|V0|V1] 8KB each per buffer);
// inner body = R21 body run twice (hh=0,1); ONE barrier pair per 128 kv. LDS 64KB/buf
// pair -> still 2 blocks/CU (128KB <= 160KB): fixed costs halve at zero occupancy cost.
__global__ __launch_bounds__(256) void attn_kernel(const unsigned short* __restrict__ Q,
                                                   const unsigned short* __restrict__ K,
                                                   const unsigned short* __restrict__ Vt,
                                                   const float* __restrict__ mask2,
                                                   float* __restrict__ out) {
  __shared__ __align__(16) char lds[65536];
  // buf*32768 + hh*8192          : K half-tile hh [64 kv][128B], slot j = chunk j^(kv&7)
  // buf*32768 + 16384 + hh*8192  : V half-tile hh [64 d][128B],  slot j = chunk j^(d&7)

  // XCD-chunked swizzle (T1), bijective over 512 blocks (512 % 8 == 0)
  int flat = blockIdx.x + 16 * (blockIdx.y + 16 * blockIdx.z);   // 0..511
  int f2 = (flat & 7) * 64 + (flat >> 3);
  const int qt = f2 & 15, h = (f2 >> 4) & 15, b = f2 >> 8;

  const int tid = threadIdx.x, w = tid >> 6, l = tid & 63;
  const int lq = l & 31, h2 = l >> 5;
  const int isV = w >> 1, half = w & 1;          // staging role
  const int srow8 = l >> 3, slot = l & 7;

  const unsigned short* Qb = Q + ((size_t)(b * 16 + h) * 2048) * 64;
  const unsigned short* Kb = K + ((size_t)(b * 16 + h) * 4096) * 64;
  const unsigned short* Vb = Vt + ((size_t)(b * 16 + h) * 64) * 4096;
  const float* mk = mask2 + (size_t)b * 4096;
  const int sq0 = qt * 128 + w * 32;

  // Q fragments (B-operand of 32x32x16): lane holds q=lq, d = ks*16 + h2*8 + j
  short8 qf[4];
#pragma unroll
  for (int ks = 0; ks < 4; ks++)
    qf[ks] = *(const short8*)(Qb + (size_t)(sq0 + lq) * 64 + ks * 16 + h2 * 8);

  // constant B-frag with B[k=0][q]=1 (h2==0, j==0 element = bf16 1.0) for the mask
  const u32x4 obp = (u32x4){(h2 == 0) ? 0x00003f80u : 0u, 0u, 0u, 0u};
  const short8 onesB = __builtin_bit_cast(short8, obp);
  // all-ones A-frag for the ls-sum MFMA
  short8 onesA;
#pragma unroll
  for (int i = 0; i < 8; i++) onesA[i] = (short)0x3f80;

  f32x16 ctx[2];
#pragma unroll
  for (int d = 0; d < 2; d++)
#pragma unroll
    for (int r = 0; r < 16; r++) ctx[d][r] = 0.f;
  f32x16 lsacc;
#pragma unroll
  for (int r = 0; r < 16; r++) lsacc[r] = 0.f;

  // ---- stage tile 0 (both 64-kv halves) into buf 0 ----
  {
#pragma unroll
    for (int hh = 0; hh < 2; hh++) {
      char* base = lds + isV * 16384 + hh * 8192;
      if (!isV) {
#pragma unroll
        for (int c = 0; c < 4; c++) {
          int kr = half * 32 + c * 8 + srow8;
          g2lds16(Kb + (size_t)(hh * 64 + kr) * 64 + (slot ^ (kr & 7)) * 8,
                  base + (half * 32 + c * 8) * 128);
        }
      } else {
#pragma unroll
        for (int c = 0; c < 4; c++) {
          int dr = half * 32 + c * 8 + srow8;
          g2lds16(Vb + (size_t)dr * 4096 + hh * 64 + (slot ^ (dr & 7)) * 8,
                  base + (half * 32 + c * 8) * 128);
        }
      }
    }
  }
  __syncthreads();

  int buf = 0;
  for (int t = 0; t < 32; t++) {
    const int s0 = t * 128;

    // mask scalars FIRST (oldest vmcnt slots; their wait leaves the DMA in flight)
    float mval[2][2];
#pragma unroll
    for (int hh = 0; hh < 2; hh++) {
      mval[hh][0] = mk[s0 + hh * 64 + lq];
      mval[hh][1] = mk[s0 + hh * 64 + 32 + lq];
    }

    // ---- issue DMA for tile t+1 into buf^1 (lands during compute below) ----
    if (t < 31) {
#pragma unroll
      for (int hh = 0; hh < 2; hh++) {
        char* base = lds + (buf ^ 1) * 32768 + isV * 16384 + hh * 8192;
        if (!isV) {
#pragma unroll
          for (int c = 0; c < 4; c++) {
            int kr = half * 32 + c * 8 + srow8;
            g2lds16(Kb + (size_t)(s0 + 128 + hh * 64 + kr) * 64 + (slot ^ (kr & 7)) * 8,
                    base + (half * 32 + c * 8) * 128);
          }
        } else {
#pragma unroll
          for (int c = 0; c < 4; c++) {
            int dr = half * 32 + c * 8 + srow8;
            g2lds16(Vb + (size_t)dr * 4096 + (s0 + 128 + hh * 64) + (slot ^ (dr & 7)) * 8,
                    base + (half * 32 + c * 8) * 128);
          }
        }
      }
    }

    // ---- two 64-kv halves per barrier pair ----
#pragma unroll
    for (int hh = 0; hh < 2; hh++) {
      const char* kbase = lds + buf * 32768 + hh * 8192;
      const char* vbase = lds + buf * 32768 + 16384 + hh * 8192;

      // QK^T per 32-kv sub; C-init = rank-1 mask MFMA; P in registers
      short8 bfr[2][2];
#pragma unroll
      for (int sub = 0; sub < 2; sub++) {
        unsigned int mw0 = (h2 == 0) ? cvtpk_bf16(mval[hh][sub], 0.f) : 0u;
        u32x4 mAp = (u32x4){mw0, 0u, 0u, 0u};
        short8 mA = __builtin_bit_cast(short8, mAp);
        f32x16 z;
#pragma unroll
        for (int r = 0; r < 16; r++) z[r] = 0.f;
        z = __builtin_amdgcn_mfma_f32_32x32x16_bf16(mA, onesB, z, 0, 0, 0);
#pragma unroll
        for (int ks = 0; ks < 4; ks++) {
          short8 kf = *(const short8*)(kbase + (sub * 32 + lq) * 128 + (((ks * 2 + h2) ^ (lq & 7)) << 4));
          z = __builtin_amdgcn_mfma_f32_32x32x16_bf16(kf, qf[ks], z, 0, 0, 0);
        }
        float p[16];
#pragma unroll
        for (int r = 0; r < 16; r++) p[r] = exp2_(z[r]);
        unsigned int X[4], Y[4];
#pragma unroll
        for (int br = 0; br < 4; br++) {
          X[br] = cvtpk_bf16(p[br * 4 + 0], p[br * 4 + 1]);
          Y[br] = cvtpk_bf16(p[br * 4 + 2], p[br * 4 + 3]);
        }
#pragma unroll
        for (int k2 = 0; k2 < 2; k2++) {
          // swap(D=X[2k2], S=X[2k2+1]): D' = w0 (j0,j1), S' = w2 (j4,j5); Y -> w1, w3.
          unsigned int xd = X[2 * k2], xs = X[2 * k2 + 1];
          asm("v_permlane32_swap_b32 %0, %1" : "+v"(xd), "+v"(xs));
          unsigned int yd = Y[2 * k2], ys = Y[2 * k2 + 1];
          asm("v_permlane32_swap_b32 %0, %1" : "+v"(yd), "+v"(ys));
          u32x4 packed = (u32x4){xd, yd, xs, ys};
          bfr[sub][k2] = __builtin_bit_cast(short8, packed);
        }
      }

      // PV + ls
#pragma unroll
      for (int dsub = 0; dsub < 2; dsub++)
#pragma unroll
        for (int sub = 0; sub < 2; sub++)
#pragma unroll
          for (int k2 = 0; k2 < 2; k2++) {
            short8 vf = *(const short8*)(vbase + (dsub * 32 + lq) * 128 +
                                         (((sub * 4 + k2 * 2 + h2) ^ (lq & 7)) << 4));
            ctx[dsub] = __builtin_amdgcn_mfma_f32_32x32x16_bf16(vf, bfr[sub][k2], ctx[dsub], 0, 0, 0);
          }
#pragma unroll
      for (int sub = 0; sub < 2; sub++)
#pragma unroll
        for (int k2 = 0; k2 < 2; k2++)
          lsacc = __builtin_amdgcn_mfma_f32_32x32x16_bf16(onesA, bfr[sub][k2], lsacc, 0, 0, 0);
    }

    __syncthreads();   // drains DMA of t+1; all waves done reading buf
    buf ^= 1;
  }

  // every lsacc row holds the full kv-sum for this lane's q
  float inv = 1.f / lsacc[0];

  // ---- epilogue: direct write (no merge) ----
  size_t orow = (size_t)(b * 2048 + sq0 + lq);
#pragma unroll
  for (int dsub = 0; dsub < 2; dsub++)
#pragma unroll
    for (int br = 0; br < 4; br++) {
      int d0 = dsub * 32 + br * 8 + h2 * 4;
      f32x4 o = (f32x4){ctx[dsub][br * 4 + 0], ctx[dsub][br * 4 + 1],
                        ctx[dsub][br * 4 + 2], ctx[dsub][br * 4 + 3]} * inv;
      *(f32x4*)(out + orow * 1024 + h * 64 + d0) = o;
    }
}

// ---------- launcher ----------
extern "C" void kernel_launch(void* const* d_in, const int* in_sizes, int n_in,
                              void* d_out, int out_size, void* d_ws, size_t ws_size,
                              hipStream_t stream) {
  const float* hid = (const float*)d_in[0];
  const float* enc = (const float*)d_in[1];
  const float* mask = (const float*)d_in[2];
  const float* Wq = (const float*)d_in[3];
  const float* bq = (const float*)d_in[4];
  const float* Wk = (const float*)d_in[5];
  const float* bk = (const float*)d_in[6];
  const float* Wv = (const float*)d_in[7];
  const float* bv = (const float*)d_in[8];

  unsigned short* ws = (unsigned short*)d_ws;
  unsigned short* WTQ = ws;                    // 1M elems (WTQ/WTK/WTV contiguous)
  unsigned short* WTK = ws + 1048576;          // 1M
  unsigned short* WTV = ws + 2097152;          // 1M
  unsigned short* AH  = ws + 3145728;          // 8M  [B][4096][1024]
  unsigned short* Qb  = ws + 11534336;         // 4M  [B][16][2048][64]
  unsigned short* Kb  = ws + 15728640;         // 8M  [B][16][4096][64]
  unsigned short* VT  = ws + 24117248;         // 8M  [B][16][64][4096]
  float* mask2 = (float*)(ws + 32505856);      // 8192 fp32

  const float QSCALE = 0.18033688011112042f;   // 0.125 * log2(e), folded into Q projection

  convert_allhs<<<8200, 256, 0, stream>>>(hid, enc, AH, mask, mask2);
  transpose_w3<<<dim3(16, 16, 3), 256, 0, stream>>>(Wq, Wk, Wv, WTQ);

  gemm_all<<<1280, 256, 0, stream>>>(WTQ, WTK, WTV, AH, bq, bk, bv, Qb, Kb, VT, QSCALE);

  attn_kernel<<<dim3(16, 16, 2), 256, 0, stream>>>(Qb, Kb, VT, mask2, (float*)d_out);
}

// Round 23
// 172.551 us; speedup vs baseline: 1.0487x; 1.0118x over previous
//
#include <hip/hip_runtime.h>
#include <hip/hip_bf16.h>
#include <stdint.h>

// B=2, SQ=2048, SE=2048, SKV=4096, H=1024, NH=16, HD=64
// fp32 in/out; internal compute bf16 MFMA.

typedef __attribute__((ext_vector_type(8))) short short8;
typedef __attribute__((ext_vector_type(4))) float f32x4;
typedef __attribute__((ext_vector_type(16))) float f32x16;
typedef __attribute__((ext_vector_type(4))) unsigned short us4;
typedef __attribute__((ext_vector_type(4))) unsigned int u32x4;

// may_alias types for LDS handoffs (R3 lesson: TBAA reorder).
typedef __attribute__((ext_vector_type(8), may_alias)) short short8a;
typedef __attribute__((ext_vector_type(4), may_alias)) float f32x4a;
typedef __attribute__((may_alias)) float floata;

#define DEV static __device__ __forceinline__

DEV unsigned short f2bf(float f) {
  unsigned int u = __builtin_bit_cast(unsigned int, f);
  u += 0x7fffu + ((u >> 16) & 1u);   // RNE
  return (unsigned short)(u >> 16);
}

DEV float exp2_(float x) {
#if __has_builtin(__builtin_amdgcn_exp2f)
  return __builtin_amdgcn_exp2f(x);
#else
  float r; asm("v_exp_f32 %0, %1" : "=v"(r) : "v"(x)); return r;
#endif
}

DEV unsigned int cvtpk_bf16(float lo, float hi) {
  unsigned int r;
  asm("v_cvt_pk_bf16_f32 %0, %1, %2" : "=v"(r) : "v"(lo), "v"(hi));
  return r;
}

DEV void g2lds16(const void* g, void* l) {
  __builtin_amdgcn_global_load_lds((const __attribute__((address_space(1))) void*)g,
                                   (__attribute__((address_space(3))) void*)l, 16, 0, 0);
}

// ---------- input conversion: all_hs -> bf16; blocks >= 8192 premultiply the mask ----------
__global__ __launch_bounds__(256) void convert_allhs(const float* __restrict__ hid,
                                                     const float* __restrict__ enc,
                                                     unsigned short* __restrict__ ah,
                                                     const float* __restrict__ mask,
                                                     float* __restrict__ mask2) {
  if (blockIdx.x >= 8192) {
    int i = (blockIdx.x - 8192) * 256 + threadIdx.x;
    f32x4 v = *(const f32x4*)(mask + i * 4);
    *(f32x4*)(mask2 + i * 4) = v * 1.4426950408889634f;
    return;
  }
  int idx = blockIdx.x * 256 + threadIdx.x;
  const int perB = 4096 * 256;
  int b = idx / perB, r = idx - b * perB;
  int s = r >> 8, c4 = r & 255;
  const float* srcrow = (s < 2048) ? hid + (size_t)(b * 2048 + s) * 1024
                                   : enc + (size_t)(b * 2048 + (s - 2048)) * 1024;
  f32x4 v = *(const f32x4*)(srcrow + c4 * 4);
  us4 o;
  o[0] = f2bf(v[0]); o[1] = f2bf(v[1]); o[2] = f2bf(v[2]); o[3] = f2bf(v[3]);
  *(us4*)(ah + (size_t)idx * 4) = o;
}

// ---------- merged weight transpose: Wt[n][k] = bf16(W[k][n]) for Wq,Wk,Wv ----------
__global__ __launch_bounds__(256) void transpose_w3(const float* __restrict__ Wq,
                                                    const float* __restrict__ Wk,
                                                    const float* __restrict__ Wv,
                                                    unsigned short* __restrict__ WtBase) {
  __shared__ unsigned short t[64][65];
  const int z = blockIdx.z;
  const float* W = (z == 0) ? Wq : (z == 1) ? Wk : Wv;
  unsigned short* Wt = WtBase + (size_t)z * 1048576;
  int k0 = blockIdx.y * 64, n0 = blockIdx.x * 64;
  int tid = threadIdx.x;
#pragma unroll
  for (int rep = 0; rep < 16; rep++) {
    int idx = rep * 256 + tid;
    int kk = idx >> 6, nn = idx & 63;
    t[kk][nn] = f2bf(W[(size_t)(k0 + kk) * 1024 + n0 + nn]);
  }
  __syncthreads();
#pragma unroll
  for (int rep = 0; rep < 16; rep++) {
    int idx = rep * 256 + tid;
    int nn = idx >> 6, kk = idx & 63;
    Wt[(size_t)(n0 + nn) * 1024 + k0 + kk] = t[kk][nn];
  }
}

// ---------- merged NT GEMM, BK=64 (R17-proven): Q + K + V in ONE 1280-block dispatch ----
__global__ __launch_bounds__(256) void gemm_all(const unsigned short* __restrict__ WTQ,
                                                const unsigned short* __restrict__ WTK,
                                                const unsigned short* __restrict__ WTV,
                                                const unsigned short* __restrict__ AH,
                                                const float* __restrict__ bq,
                                                const float* __restrict__ bk,
                                                const float* __restrict__ bv,
                                                unsigned short* __restrict__ Qout,
                                                unsigned short* __restrict__ Kout,
                                                unsigned short* __restrict__ Vout,
                                                float qscale) {
  __shared__ unsigned short ldsA[2][128 * 32];   // [k-sub][row][32k]
  __shared__ unsigned short ldsB[2][128 * 32];

  int id = blockIdx.x;
  int f2 = (id & 7) * 160 + (id >> 3);

  const unsigned short *A, *Bm;
  const float* bias;
  unsigned short* outb;
  int S, mode, r0, c0;
  float osc = 1.0f;
  if (f2 < 256) {                       // Q
    int t = f2;
    int b = t >> 7; t &= 127;
    c0 = (t & 15) * 128; r0 = (t >> 4) * 128;
    A = WTQ; Bm = AH + (size_t)b * 4194304; bias = bq;
    outb = Qout + (size_t)b * 2097152; S = 2048; mode = 0; osc = qscale;
  } else if (f2 < 768) {                // K
    int t = f2 - 256;
    int b = t >> 8; t &= 255;
    c0 = (t & 31) * 128; r0 = (t >> 5) * 128;
    A = WTK; Bm = AH + (size_t)b * 4194304; bias = bk;
    outb = Kout + (size_t)b * 4194304; S = 4096; mode = 0;
  } else {                              // V (transposed out)
    int t = f2 - 768;
    int b = t >> 8; t &= 255;
    c0 = (t & 7) * 128; r0 = (t >> 3) * 128;
    A = AH + (size_t)b * 4194304; Bm = WTV; bias = bv;
    outb = Vout + (size_t)b * 4194304; S = 4096; mode = 1;
  }

  const int tid = threadIdx.x, w = tid >> 6, l = tid & 63;
  const int wr = w >> 1, wc = w & 1;
  const int lrow = l >> 2;                       // 4 lanes per row
  const int lc = l & 15, g = l >> 4;

  f32x4 acc[4][4];
#pragma unroll
  for (int i = 0; i < 4; i++)
#pragma unroll
    for (int j = 0; j < 4; j++) acc[i][j] = (f32x4){0.f, 0.f, 0.f, 0.f};

  for (int k0 = 0; k0 < 1024; k0 += 64) {
#pragma unroll
    for (int c = 0; c < 4; c++) {
      const int cc = w * 4 + c;
      const int sub = cc & 1, rr = (cc >> 1) * 16 + lrow;
      const int kc = sub * 4 + (l & 3);
      g2lds16(A + (size_t)(r0 + rr) * 1024 + k0 + kc * 8,
              (char*)ldsA + sub * 8192 + (cc >> 1) * 1024);
      g2lds16(Bm + (size_t)(c0 + rr) * 1024 + k0 + kc * 8,
              (char*)ldsB + sub * 8192 + (cc >> 1) * 1024);
    }
    __syncthreads();
#pragma unroll
    for (int kk = 0; kk < 2; kk++) {
      short8 af[4], bf[4];
#pragma unroll
      for (int f = 0; f < 4; f++) {
        af[f] = *(const short8*)((const char*)ldsA + kk * 8192 + (wr * 64 + f * 16 + lc) * 64 + g * 16);
        bf[f] = *(const short8*)((const char*)ldsB + kk * 8192 + (wc * 64 + f * 16 + lc) * 64 + g * 16);
      }
#pragma unroll
      for (int fr = 0; fr < 4; fr++)
#pragma unroll
        for (int fc = 0; fc < 4; fc++)
          acc[fr][fc] = __builtin_amdgcn_mfma_f32_16x16x32_bf16(af[fr], bf[fc], acc[fr][fc], 0, 0, 0);
    }
    __syncthreads();
  }

#pragma unroll
  for (int fr = 0; fr < 4; fr++) {
    int rb = r0 + wr * 64 + fr * 16 + g * 4;
    float bv4[4];
    if (mode == 0) {
#pragma unroll
      for (int i = 0; i < 4; i++) bv4[i] = bias[rb + i];
    }
#pragma unroll
    for (int fc = 0; fc < 4; fc++) {
      int c = c0 + wc * 64 + fc * 16 + lc;
      float bc = (mode == 0) ? 0.f : bias[c];
      us4 pk;
#pragma unroll
      for (int i = 0; i < 4; i++) {
        float v = (acc[fr][fc][i] + (mode == 0 ? bv4[i] : bc)) * osc;
        pk[i] = f2bf(v);
      }
      size_t addr;
      if (mode == 0) addr = ((size_t)(rb >> 6) * S + c) * 64 + (rb & 63);
      else           addr = (size_t)c * S + rb;
      *(us4*)(outb + addr) = pk;
    }
  }
}

// ---------- flash attention v23: 128-kv tiles, cross-half reorder QK0,QK1,PV0,PV1 ----------
// R22: MfmaUtil 38 / VALU 47 -- the matrix pipe idles during each softmax tail.
// QK(hh=1) is fully independent of SM(hh=0): reorder so the scheduler can hoist
// QK1's kf-reads/MFMAs into SM0's VALU shadow, and PV0+PV1 form one MFMA cluster.
// All 8 bfr fragments held across the tile (+16 VGPR transient). Pure program-order
// change: no sync-structure edits, layouts verbatim from R22.
__global__ __launch_bounds__(256) void attn_kernel(const unsigned short* __restrict__ Q,
                                                   const unsigned short* __restrict__ K,
                                                   const unsigned short* __restrict__ Vt,
                                                   const float* __restrict__ mask2,
                                                   float* __restrict__ out) {
  __shared__ __align__(16) char lds[65536];
  // buf*32768 + hh*8192          : K half-tile hh [64 kv][128B], slot j = chunk j^(kv&7)
  // buf*32768 + 16384 + hh*8192  : V half-tile hh [64 d][128B],  slot j = chunk j^(d&7)

  // XCD-chunked swizzle (T1), bijective over 512 blocks (512 % 8 == 0)
  int flat = blockIdx.x + 16 * (blockIdx.y + 16 * blockIdx.z);   // 0..511
  int f2 = (flat & 7) * 64 + (flat >> 3);
  const int qt = f2 & 15, h = (f2 >> 4) & 15, b = f2 >> 8;

  const int tid = threadIdx.x, w = tid >> 6, l = tid & 63;
  const int lq = l & 31, h2 = l >> 5;
  const int isV = w >> 1, half = w & 1;          // staging role
  const int srow8 = l >> 3, slot = l & 7;

  const unsigned short* Qb = Q + ((size_t)(b * 16 + h) * 2048) * 64;
  const unsigned short* Kb = K + ((size_t)(b * 16 + h) * 4096) * 64;
  const unsigned short* Vb = Vt + ((size_t)(b * 16 + h) * 64) * 4096;
  const float* mk = mask2 + (size_t)b * 4096;
  const int sq0 = qt * 128 + w * 32;

  // Q fragments (B-operand of 32x32x16): lane holds q=lq, d = ks*16 + h2*8 + j
  short8 qf[4];
#pragma unroll
  for (int ks = 0; ks < 4; ks++)
    qf[ks] = *(const short8*)(Qb + (size_t)(sq0 + lq) * 64 + ks * 16 + h2 * 8);

  // constant B-frag with B[k=0][q]=1 (h2==0, j==0 element = bf16 1.0) for the mask
  const u32x4 obp = (u32x4){(h2 == 0) ? 0x00003f80u : 0u, 0u, 0u, 0u};
  const short8 onesB = __builtin_bit_cast(short8, obp);
  // all-ones A-frag for the ls-sum MFMA
  short8 onesA;
#pragma unroll
  for (int i = 0; i < 8; i++) onesA[i] = (short)0x3f80;

  f32x16 ctx[2];
#pragma unroll
  for (int d = 0; d < 2; d++)
#pragma unroll
    for (int r = 0; r < 16; r++) ctx[d][r] = 0.f;
  f32x16 lsacc;
#pragma unroll
  for (int r = 0; r < 16; r++) lsacc[r] = 0.f;

  // ---- stage tile 0 (both 64-kv halves) into buf 0 ----
  {
#pragma unroll
    for (int hh = 0; hh < 2; hh++) {
      char* base = lds + isV * 16384 + hh * 8192;
      if (!isV) {
#pragma unroll
        for (int c = 0; c < 4; c++) {
          int kr = half * 32 + c * 8 + srow8;
          g2lds16(Kb + (size_t)(hh * 64 + kr) * 64 + (slot ^ (kr & 7)) * 8,
                  base + (half * 32 + c * 8) * 128);
        }
      } else {
#pragma unroll
        for (int c = 0; c < 4; c++) {
          int dr = half * 32 + c * 8 + srow8;
          g2lds16(Vb + (size_t)dr * 4096 + hh * 64 + (slot ^ (dr & 7)) * 8,
                  base + (half * 32 + c * 8) * 128);
        }
      }
    }
  }
  __syncthreads();

  int buf = 0;
  for (int t = 0; t < 32; t++) {
    const int s0 = t * 128;

    // mask scalars FIRST (oldest vmcnt slots; their wait leaves the DMA in flight)
    float mval[2][2];
#pragma unroll
    for (int hh = 0; hh < 2; hh++) {
      mval[hh][0] = mk[s0 + hh * 64 + lq];
      mval[hh][1] = mk[s0 + hh * 64 + 32 + lq];
    }

    // ---- issue DMA for tile t+1 into buf^1 (lands during compute below) ----
    if (t < 31) {
#pragma unroll
      for (int hh = 0; hh < 2; hh++) {
        char* base = lds + (buf ^ 1) * 32768 + isV * 16384 + hh * 8192;
        if (!isV) {
#pragma unroll
          for (int c = 0; c < 4; c++) {
            int kr = half * 32 + c * 8 + srow8;
            g2lds16(Kb + (size_t)(s0 + 128 + hh * 64 + kr) * 64 + (slot ^ (kr & 7)) * 8,
                    base + (half * 32 + c * 8) * 128);
          }
        } else {
#pragma unroll
          for (int c = 0; c < 4; c++) {
            int dr = half * 32 + c * 8 + srow8;
            g2lds16(Vb + (size_t)dr * 4096 + (s0 + 128 + hh * 64) + (slot ^ (dr & 7)) * 8,
                    base + (half * 32 + c * 8) * 128);
          }
        }
      }
    }

    // ---- phase 1: QK + softmax for BOTH halves (hh=1's MFMAs overlap hh=0's VALU) ----
    short8 bfr[2][2][2];   // [hh][sub][k2] PV B-fragments
#pragma unroll
    for (int hh = 0; hh < 2; hh++) {
      const char* kbase = lds + buf * 32768 + hh * 8192;
#pragma unroll
      for (int sub = 0; sub < 2; sub++) {
        unsigned int mw0 = (h2 == 0) ? cvtpk_bf16(mval[hh][sub], 0.f) : 0u;
        u32x4 mAp = (u32x4){mw0, 0u, 0u, 0u};
        short8 mA = __builtin_bit_cast(short8, mAp);
        f32x16 z;
#pragma unroll
        for (int r = 0; r < 16; r++) z[r] = 0.f;
        z = __builtin_amdgcn_mfma_f32_32x32x16_bf16(mA, onesB, z, 0, 0, 0);
#pragma unroll
        for (int ks = 0; ks < 4; ks++) {
          short8 kf = *(const short8*)(kbase + (sub * 32 + lq) * 128 + (((ks * 2 + h2) ^ (lq & 7)) << 4));
          z = __builtin_amdgcn_mfma_f32_32x32x16_bf16(kf, qf[ks], z, 0, 0, 0);
        }
        float p[16];
#pragma unroll
        for (int r = 0; r < 16; r++) p[r] = exp2_(z[r]);
        unsigned int X[4], Y[4];
#pragma unroll
        for (int br = 0; br < 4; br++) {
          X[br] = cvtpk_bf16(p[br * 4 + 0], p[br * 4 + 1]);
          Y[br] = cvtpk_bf16(p[br * 4 + 2], p[br * 4 + 3]);
        }
#pragma unroll
        for (int k2 = 0; k2 < 2; k2++) {
          // swap(D=X[2k2], S=X[2k2+1]): D' = w0 (j0,j1), S' = w2 (j4,j5); Y -> w1, w3.
          unsigned int xd = X[2 * k2], xs = X[2 * k2 + 1];
          asm("v_permlane32_swap_b32 %0, %1" : "+v"(xd), "+v"(xs));
          unsigned int yd = Y[2 * k2], ys = Y[2 * k2 + 1];
          asm("v_permlane32_swap_b32 %0, %1" : "+v"(yd), "+v"(ys));
          u32x4 packed = (u32x4){xd, yd, xs, ys};
          bfr[hh][sub][k2] = __builtin_bit_cast(short8, packed);
        }
      }
    }

    // ---- phase 2: PV + ls for both halves (one long MFMA cluster) ----
#pragma unroll
    for (int hh = 0; hh < 2; hh++) {
      const char* vbase = lds + buf * 32768 + 16384 + hh * 8192;
#pragma unroll
      for (int dsub = 0; dsub < 2; dsub++)
#pragma unroll
        for (int sub = 0; sub < 2; sub++)
#pragma unroll
          for (int k2 = 0; k2 < 2; k2++) {
            short8 vf = *(const short8*)(vbase + (dsub * 32 + lq) * 128 +
                                         (((sub * 4 + k2 * 2 + h2) ^ (lq & 7)) << 4));
            ctx[dsub] = __builtin_amdgcn_mfma_f32_32x32x16_bf16(vf, bfr[hh][sub][k2], ctx[dsub], 0, 0, 0);
          }
#pragma unroll
      for (int sub = 0; sub < 2; sub++)
#pragma unroll
        for (int k2 = 0; k2 < 2; k2++)
          lsacc = __builtin_amdgcn_mfma_f32_32x32x16_bf16(onesA, bfr[hh][sub][k2], lsacc, 0, 0, 0);
    }

    __syncthreads();   // drains DMA of t+1; all waves done reading buf
    buf ^= 1;
  }

  // every lsacc row holds the full kv-sum for this lane's q
  float inv = 1.f / lsacc[0];

  // ---- epilogue: direct write (no merge) ----
  size_t orow = (size_t)(b * 2048 + sq0 + lq);
#pragma unroll
  for (int dsub = 0; dsub < 2; dsub++)
#pragma unroll
    for (int br = 0; br < 4; br++) {
      int d0 = dsub * 32 + br * 8 + h2 * 4;
      f32x4 o = (f32x4){ctx[dsub][br * 4 + 0], ctx[dsub][br * 4 + 1],
                        ctx[dsub][br * 4 + 2], ctx[dsub][br * 4 + 3]} * inv;
      *(f32x4*)(out + orow * 1024 + h * 64 + d0) = o;
    }
}

// ---------- launcher ----------
extern "C" void kernel_launch(void* const* d_in, const int* in_sizes, int n_in,
                              void* d_out, int out_size, void* d_ws, size_t ws_size,
                              hipStream_t stream) {
  const float* hid = (const float*)d_in[0];
  const float* enc = (const float*)d_in[1];
  const float* mask = (const float*)d_in[2];
  const float* Wq = (const float*)d_in[3];
  const float* bq = (const float*)d_in[4];
  const float* Wk = (const float*)d_in[5];
  const float* bk = (const float*)d_in[6];
  const float* Wv = (const float*)d_in[7];
  const float* bv = (const float*)d_in[8];

  unsigned short* ws = (unsigned short*)d_ws;
  unsigned short* WTQ = ws;                    // 1M elems (WTQ/WTK/WTV contiguous)
  unsigned short* WTK = ws + 1048576;          // 1M
  unsigned short* WTV = ws + 2097152;          // 1M
  unsigned short* AH  = ws + 3145728;          // 8M  [B][4096][1024]
  unsigned short* Qb  = ws + 11534336;         // 4M  [B][16][2048][64]
  unsigned short* Kb  = ws + 15728640;         // 8M  [B][16][4096][64]
  unsigned short* VT  = ws + 24117248;         // 8M  [B][16][64][4096]
  float* mask2 = (float*)(ws + 32505856);      // 8192 fp32

  const float QSCALE = 0.18033688011112042f;   // 0.125 * log2(e), folded into Q projection

  convert_allhs<<<8200, 256, 0, stream>>>(hid, enc, AH, mask, mask2);
  transpose_w3<<<dim3(16, 16, 3), 256, 0, stream>>>(Wq, Wk, Wv, WTQ);

  gemm_all<<<1280, 256, 0, stream>>>(WTQ, WTK, WTV, AH, bq, bk, bv, Qb, Kb, VT, QSCALE);

  attn_kernel<<<dim3(16, 16, 2), 256, 0, stream>>>(Qb, Kb, VT, mask2, (float*)d_out);
}